// Round 5
// baseline (1027.922 us; speedup 1.0000x reference)
//
#include <hip/hip_runtime.h>
#include <hip/hip_bf16.h>
#include <stdint.h>
#include <stdio.h>

// All tensors are FLOAT32 (reference uses jnp.float32 throughout).
// Pipeline: three kernels, activations carried between stages as 2-bit codes
// (uint8) in d_ws. All dot products accumulate integer-valued floats / ints,
// scales folded in once at the end => numerically within ~1e-7 of np f32 ref.

// ---------------------------------------------------------------------------
// Stage 1: quant_identity_2b(x) -> conv1(binary w1) + b1 -> maxpool2 -> BN1
//          -> quant_relu_2b  => a1 codes {0..3}, layout [B][6][14][14]
// Pool done on the integer conv sum S (affine map with positive slope is
// monotone; correctly-rounded monotone map preserves max) then affine+quant.
// ---------------------------------------------------------------------------
__global__ __launch_bounds__(256) void k_stage1(
    const float* __restrict__ x, const float* __restrict__ w1,
    const float* __restrict__ b1, const float* __restrict__ bn1s,
    const float* __restrict__ bn1b, const float* __restrict__ p_sin,
    const float* __restrict__ p_sw1, const float* __restrict__ p_sa1,
    uint8_t* __restrict__ a1)
{
    const int b   = blockIdx.x;
    const int tid = threadIdx.x;

    __shared__ float q[3][32][32];      // quantized input codes {-2,-1,0,1}
    __shared__ float w[6][3][5][5];     // binarized weights +-1
    __shared__ float cb[6], cs[6], cbb[6];

    const float s_in = p_sin[0];
    const float s_a1 = p_sa1[0];
    const float c1   = __fmul_rn(s_in, p_sw1[0]);

    const float* xb = x + (size_t)b * 3072;
    float* qf = &q[0][0][0];
    for (int i = tid; i < 3072; i += 256) {
        float r = rintf(__fdiv_rn(xb[i], s_in));  // rintf = half-to-even (np.round)
        qf[i] = fminf(fmaxf(r, -2.f), 1.f);
    }
    float* wf = &w[0][0][0][0];
    for (int i = tid; i < 450; i += 256)
        wf[i] = (w1[i] >= 0.f) ? 1.f : -1.f;      // -0.0 -> +1, matches np
    if (tid < 6) {
        cb[tid]  = b1[tid];
        cs[tid]  = bn1s[tid];
        cbb[tid] = bn1b[tid];
    }
    __syncthreads();

    for (int o = tid; o < 6 * 14 * 14; o += 256) {
        const int c  = o / 196;
        const int r  = o - c * 196;
        const int py = r / 14;
        const int px = r - py * 14;
        const int oy = 2 * py, ox = 2 * px;

        float S00 = 0.f, S01 = 0.f, S10 = 0.f, S11 = 0.f;
        #pragma unroll
        for (int ci = 0; ci < 3; ++ci)
            #pragma unroll
            for (int ky = 0; ky < 5; ++ky)
                #pragma unroll
                for (int kx = 0; kx < 5; ++kx) {
                    const float wv = w[c][ci][ky][kx];
                    S00 = __builtin_fmaf(wv, q[ci][oy + ky]    [ox + kx],     S00);
                    S01 = __builtin_fmaf(wv, q[ci][oy + ky]    [ox + 1 + kx], S01);
                    S10 = __builtin_fmaf(wv, q[ci][oy + 1 + ky][ox + kx],     S10);
                    S11 = __builtin_fmaf(wv, q[ci][oy + 1 + ky][ox + 1 + kx], S11);
                }
        const float m = fmaxf(fmaxf(S00, S01), fmaxf(S10, S11));

        const float y = __fadd_rn(__fmul_rn(m, c1), cb[c]);       // conv scale+bias
        const float z = __fadd_rn(__fmul_rn(y, cs[c]), cbb[c]);   // BN mul then add
        const float t = __fdiv_rn(fmaxf(z, 0.f), s_a1);
        const float k = fminf(fmaxf(rintf(t), 0.f), 3.f);
        a1[(size_t)b * 1176 + o] = (uint8_t)k;
    }
}

// ---------------------------------------------------------------------------
// Stage 2: conv2(binary w2) + b2 -> maxpool2 -> BN2 -> quant_relu_2b
//          a1 [B][6][14][14] codes -> a2 [B][16][5][5] codes (flatten order)
// ---------------------------------------------------------------------------
__global__ __launch_bounds__(256) void k_stage2(
    const uint8_t* __restrict__ a1, const float* __restrict__ w2,
    const float* __restrict__ b2, const float* __restrict__ bn2s,
    const float* __restrict__ bn2b, const float* __restrict__ p_sa1,
    const float* __restrict__ p_sw2, const float* __restrict__ p_sa2,
    uint8_t* __restrict__ a2)
{
    const int b   = blockIdx.x;
    const int tid = threadIdx.x;

    __shared__ float a[6][14][14];
    __shared__ float w[16][6][5][5];
    __shared__ float cb[16], cs[16], cbb[16];

    const float c2   = __fmul_rn(p_sa1[0], p_sw2[0]);
    const float s_a2 = p_sa2[0];

    const uint8_t* ab = a1 + (size_t)b * 1176;
    float* af = &a[0][0][0];
    for (int i = tid; i < 1176; i += 256) af[i] = (float)(int)ab[i];
    float* wfp = &w[0][0][0][0];
    for (int i = tid; i < 2400; i += 256)
        wfp[i] = (w2[i] >= 0.f) ? 1.f : -1.f;
    if (tid < 16) {
        cb[tid]  = b2[tid];
        cs[tid]  = bn2s[tid];
        cbb[tid] = bn2b[tid];
    }
    __syncthreads();

    for (int o = tid; o < 400; o += 256) {
        const int c  = o / 25;
        const int r  = o - c * 25;
        const int py = r / 5;
        const int px = r - py * 5;
        const int oy = 2 * py, ox = 2 * px;

        float S00 = 0.f, S01 = 0.f, S10 = 0.f, S11 = 0.f;
        for (int ci = 0; ci < 6; ++ci)
            #pragma unroll
            for (int ky = 0; ky < 5; ++ky)
                #pragma unroll
                for (int kx = 0; kx < 5; ++kx) {
                    const float wv = w[c][ci][ky][kx];
                    S00 = __builtin_fmaf(wv, a[ci][oy + ky]    [ox + kx],     S00);
                    S01 = __builtin_fmaf(wv, a[ci][oy + ky]    [ox + 1 + kx], S01);
                    S10 = __builtin_fmaf(wv, a[ci][oy + 1 + ky][ox + kx],     S10);
                    S11 = __builtin_fmaf(wv, a[ci][oy + 1 + ky][ox + 1 + kx], S11);
                }
        const float m = fmaxf(fmaxf(S00, S01), fmaxf(S10, S11));

        const float y = __fadd_rn(__fmul_rn(m, c2), cb[c]);
        const float z = __fadd_rn(__fmul_rn(y, cs[c]), cbb[c]);
        const float t = __fdiv_rn(fmaxf(z, 0.f), s_a2);
        const float k = fminf(fmaxf(rintf(t), 0.f), 3.f);
        a2[(size_t)b * 400 + o] = (uint8_t)k;     // channel-major flatten order
    }
}

// ---------------------------------------------------------------------------
// Stage 3: fc1 (100x400) -> quant_relu -> fc2 (50x100) -> quant_relu
//          -> fc3 (10x50) + fb3 -> f32 out.  16 samples per block.
// ---------------------------------------------------------------------------
#define SPB 16
__global__ __launch_bounds__(256) void k_fc(
    const uint8_t* __restrict__ a2,
    const float* __restrict__ fw1, const float* __restrict__ fb1,
    const float* __restrict__ fw2, const float* __restrict__ fb2,
    const float* __restrict__ fw3, const float* __restrict__ fb3,
    const float* __restrict__ p_sa2, const float* __restrict__ p_sfw1,
    const float* __restrict__ p_sfw2, const float* __restrict__ p_sfw3,
    const float* __restrict__ p_sa3, const float* __restrict__ p_sa4,
    float* __restrict__ out)
{
    const int b0  = blockIdx.x * SPB;
    const int tid = threadIdx.x;

    __shared__ int8_t w1s[100 * 400];
    __shared__ int8_t w2s[50 * 100];
    __shared__ int8_t w3s[10 * 50];
    __shared__ float  bb1[100], bb2[50], bb3[12];
    __shared__ int8_t xs[SPB][400];
    __shared__ int8_t h1[SPB][100];
    __shared__ int8_t h2[SPB][52];

    for (int i = tid; i < 40000; i += 256) w1s[i] = (fw1[i] >= 0.f) ? 1 : -1;
    for (int i = tid; i < 5000;  i += 256) w2s[i] = (fw2[i] >= 0.f) ? 1 : -1;
    for (int i = tid; i < 500;   i += 256) w3s[i] = (fw3[i] >= 0.f) ? 1 : -1;
    for (int i = tid; i < 100;   i += 256) bb1[i] = fb1[i];
    if (tid < 50) bb2[tid] = fb2[tid];
    if (tid < 10) bb3[tid] = fb3[tid];
    for (int i = tid; i < SPB * 400; i += 256)
        xs[i / 400][i % 400] = (int8_t)a2[(size_t)b0 * 400 + i];

    const float c3   = __fmul_rn(p_sa2[0], p_sfw1[0]);
    const float c4   = __fmul_rn(p_sa3[0], p_sfw2[0]);
    const float c5   = __fmul_rn(p_sa4[0], p_sfw3[0]);
    const float s_a3 = p_sa3[0];
    const float s_a4 = p_sa4[0];
    __syncthreads();

    // fc1 + quant_relu_2b(s_a3)
    for (int t = tid; t < SPB * 100; t += 256) {
        const int s = t % SPB;
        const int o = t / SPB;
        int T = 0;
        const int8_t* wr = &w1s[o * 400];
        const int8_t* xr = &xs[s][0];
        #pragma unroll 8
        for (int k = 0; k < 400; ++k) T += (int)wr[k] * (int)xr[k];
        const float y  = __fadd_rn(__fmul_rn((float)T, c3), bb1[o]);
        const float t2 = __fdiv_rn(fmaxf(y, 0.f), s_a3);
        h1[s][o] = (int8_t)fminf(fmaxf(rintf(t2), 0.f), 3.f);
    }
    __syncthreads();

    // fc2 + quant_relu_2b(s_a4)
    for (int t = tid; t < SPB * 50; t += 256) {
        const int s = t % SPB;
        const int o = t / SPB;
        int T = 0;
        const int8_t* wr = &w2s[o * 100];
        #pragma unroll 4
        for (int k = 0; k < 100; ++k) T += (int)wr[k] * (int)h1[s][k];
        const float y  = __fadd_rn(__fmul_rn((float)T, c4), bb2[o]);
        const float t2 = __fdiv_rn(fmaxf(y, 0.f), s_a4);
        h2[s][o] = (int8_t)fminf(fmaxf(rintf(t2), 0.f), 3.f);
    }
    __syncthreads();

    // fc3 (no quant)
    for (int t = tid; t < SPB * 10; t += 256) {
        const int s = t % SPB;
        const int o = t / SPB;
        int T = 0;
        const int8_t* wr = &w3s[o * 50];
        #pragma unroll
        for (int k = 0; k < 50; ++k) T += (int)wr[k] * (int)h2[s][k];
        const float y = __fadd_rn(__fmul_rn((float)T, c5), bb3[o]);
        out[(size_t)(b0 + s) * 10 + o] = y;
    }
}

// ---------------------------------------------------------------------------
extern "C" void kernel_launch(void* const* d_in, const int* in_sizes, int n_in,
                              void* d_out, int out_size, void* d_ws, size_t ws_size,
                              hipStream_t stream)
{
    // Confirmed by R4 diagnostics: in_sizes is int32, dict order (x first):
    // 50331648,450,6,2400,16,40000,100,5000,50,500,10,6,6,16,16,1x10
    const float* x    = (const float*)d_in[0];
    const float* w1   = (const float*)d_in[1];
    const float* b1   = (const float*)d_in[2];
    const float* w2   = (const float*)d_in[3];
    const float* b2   = (const float*)d_in[4];
    const float* fw1  = (const float*)d_in[5];
    const float* fb1  = (const float*)d_in[6];
    const float* fw2  = (const float*)d_in[7];
    const float* fb2  = (const float*)d_in[8];
    const float* fw3  = (const float*)d_in[9];
    const float* fb3  = (const float*)d_in[10];
    const float* bn1s = (const float*)d_in[11];
    const float* bn1b = (const float*)d_in[12];
    const float* bn2s = (const float*)d_in[13];
    const float* bn2b = (const float*)d_in[14];
    const float* s_in = (const float*)d_in[15];
    const float* s_w1 = (const float*)d_in[16];
    const float* s_w2 = (const float*)d_in[17];
    const float* s_fw1= (const float*)d_in[18];
    const float* s_fw2= (const float*)d_in[19];
    const float* s_fw3= (const float*)d_in[20];
    const float* s_a1 = (const float*)d_in[21];
    const float* s_a2 = (const float*)d_in[22];
    const float* s_a3 = (const float*)d_in[23];
    const float* s_a4 = (const float*)d_in[24];

    int B = out_size / 10;
    if (B <= 0) B = 16384;

    uint8_t* a1 = (uint8_t*)d_ws;                // B * 1176 bytes
    uint8_t* a2 = a1 + (size_t)B * 1176;         // B * 400 bytes

    k_stage1<<<B, 256, 0, stream>>>(x, w1, b1, bn1s, bn1b, s_in, s_w1, s_a1, a1);
    k_stage2<<<B, 256, 0, stream>>>(a1, w2, b2, bn2s, bn2b, s_a1, s_w2, s_a2, a2);
    k_fc<<<(B + SPB - 1) / SPB, 256, 0, stream>>>(a2, fw1, fb1, fw2, fb2, fw3, fb3,
                                                  s_a2, s_fw1, s_fw2, s_fw3, s_a3, s_a4,
                                                  (float*)d_out);
}

// Round 6
// 518.204 us; speedup vs baseline: 1.9836x; 1.9836x over previous
//
#include <hip/hip_runtime.h>
#include <stdint.h>

typedef uint32_t u32;

// v_dot4_i32_i8: D = sum of signed byte products + C (CDNA VOP3P, used by CK on gfx94x+)
#if defined(__has_builtin) && __has_builtin(__builtin_amdgcn_sdot4)
#define SDOT4(a,b,c) __builtin_amdgcn_sdot4((int)(a),(int)(b),(c),false)
#else
__device__ __forceinline__ int sdot4_sw(u32 a, u32 b, int c) {
    c += (int)(int8_t)(a)       * (int)(int8_t)(b);
    c += (int)(int8_t)(a >> 8)  * (int)(int8_t)(b >> 8);
    c += (int)(int8_t)(a >> 16) * (int)(int8_t)(b >> 16);
    c += (int)(int8_t)(a >> 24) * (int)(int8_t)(b >> 24);
    return c;
}
#define SDOT4(a,b,c) sdot4_sw((a),(b),(c))
#endif

// bytes (lo..hi) starting at byte s of the pair -> compiler emits v_alignbyte_b32
__device__ __forceinline__ u32 alignb(u32 hi, u32 lo, unsigned s) {
    return (u32)((((uint64_t)hi << 32) | lo) >> (8u * s));
}
__device__ __forceinline__ u32 sgnb(float v) { return (v >= 0.f) ? 0x01u : 0xFFu; }

// ---------------------------------------------------------------------------
// Prep: binarize+pack all weights once.
// w1p: [6][3][5] rows -> 2 words (wA = kx0..3, wB = kx4,0,0,0)      (180 words)
// w2p: [16][6][5] rows -> 2 words                                   (960 words)
// fw1p: 100x400 bytes -> 10000 words ; fw2p: 50x100 -> 1250 words
// fw3p: rows padded K 50->52 -> 10x13 words
// ---------------------------------------------------------------------------
__global__ __launch_bounds__(256) void k_prep(
    const float* __restrict__ w1, const float* __restrict__ w2,
    const float* __restrict__ fw1, const float* __restrict__ fw2,
    const float* __restrict__ fw3,
    u32* __restrict__ w1p, u32* __restrict__ w2p, u32* __restrict__ fw1p,
    u32* __restrict__ fw2p, u32* __restrict__ fw3p)
{
    const int tid = threadIdx.x;
    for (int i = tid; i < 90; i += 256) {
        const float* r = w1 + i * 5;
        w1p[i*2]   = sgnb(r[0]) | (sgnb(r[1])<<8) | (sgnb(r[2])<<16) | (sgnb(r[3])<<24);
        w1p[i*2+1] = sgnb(r[4]);
    }
    for (int i = tid; i < 480; i += 256) {
        const float* r = w2 + i * 5;
        w2p[i*2]   = sgnb(r[0]) | (sgnb(r[1])<<8) | (sgnb(r[2])<<16) | (sgnb(r[3])<<24);
        w2p[i*2+1] = sgnb(r[4]);
    }
    for (int i = tid; i < 10000; i += 256) {
        const float* r = fw1 + i * 4;   // flat: rows are 100 words contiguous
        fw1p[i] = sgnb(r[0]) | (sgnb(r[1])<<8) | (sgnb(r[2])<<16) | (sgnb(r[3])<<24);
    }
    for (int i = tid; i < 1250; i += 256) {
        const float* r = fw2 + i * 4;
        fw2p[i] = sgnb(r[0]) | (sgnb(r[1])<<8) | (sgnb(r[2])<<16) | (sgnb(r[3])<<24);
    }
    for (int i = tid; i < 130; i += 256) {
        const int o = i / 13, j = i % 13;
        u32 v = 0;
        #pragma unroll
        for (int m = 0; m < 4; ++m) {
            const int k = 4*j + m;
            if (k < 50) v |= sgnb(fw3[o*50 + k]) << (8*m);
        }
        fw3p[i] = v;
    }
}

// ---------------------------------------------------------------------------
// Conv1: quant_2b(x) -> conv(5x5,3->6) -> maxpool2 -> BN -> relu-quant2b
// 3 samples/block. Thread = (sample, c, pooled_row). Codes packed int8 in LDS,
// sdot4 over sliding 4-byte windows; integer sums identical to R5 kernel.
// a1 out: [B][6][14] rows of 16 bytes (cols 14,15 = 0).
// ---------------------------------------------------------------------------
#define NS1 3
__global__ __launch_bounds__(256) void k_conv1(
    const float* __restrict__ x, const u32* __restrict__ w1p,
    const float* __restrict__ b1, const float* __restrict__ bn1s,
    const float* __restrict__ bn1b, const float* __restrict__ p_sin,
    const float* __restrict__ p_sw1, const float* __restrict__ p_sa1,
    uint8_t* __restrict__ a1, int B)
{
    __shared__ u32 q[NS1*768];          // [sl][ci][row32][8 words]
    __shared__ u32 wp[180];
    __shared__ float cb[6], cs[6], cbb[6];
    const int tid = threadIdx.x;
    const long long b0 = (long long)blockIdx.x * NS1;

    const float s_in = p_sin[0], s_a1 = p_sa1[0];
    const float c1 = __fmul_rn(s_in, p_sw1[0]);

    if (tid < 180) wp[tid] = w1p[tid];
    else if (tid >= 192 && tid < 198) {
        const int c = tid - 192;
        cb[c] = b1[c]; cs[c] = bn1s[c]; cbb[c] = bn1b[c];
    }

    const long long wbase = b0 * 768;   // float4 index == packed-word index
    for (int i = tid; i < NS1*768; i += 256) {
        if (wbase + i < (long long)B * 768) {
            const float4 v = *(const float4*)(x + (wbase + i) * 4);
            float r0 = fminf(fmaxf(rintf(__fdiv_rn(v.x, s_in)), -2.f), 1.f);
            float r1 = fminf(fmaxf(rintf(__fdiv_rn(v.y, s_in)), -2.f), 1.f);
            float r2 = fminf(fmaxf(rintf(__fdiv_rn(v.z, s_in)), -2.f), 1.f);
            float r3 = fminf(fmaxf(rintf(__fdiv_rn(v.w, s_in)), -2.f), 1.f);
            q[i] = ((u32)(uint8_t)(int8_t)(int)r0)
                 | ((u32)(uint8_t)(int8_t)(int)r1 << 8)
                 | ((u32)(uint8_t)(int8_t)(int)r2 << 16)
                 | ((u32)(uint8_t)(int8_t)(int)r3 << 24);
        }
    }
    __syncthreads();

    if (tid < NS1*84) {
        const int sl = tid / 84, o = tid % 84, c = o / 14, py = o % 14;
        const long long b = b0 + sl;
        if (b < B) {
            int acc0[28], acc1[28];
            #pragma unroll
            for (int p = 0; p < 28; ++p) { acc0[p] = 0; acc1[p] = 0; }
            #pragma unroll
            for (int ci = 0; ci < 3; ++ci) {
                const u32* base = &q[(sl*3 + ci) * 256];
                const u32* wrow = &wp[(c*3 + ci) * 10];
                #pragma unroll
                for (int ir = 0; ir < 6; ++ir) {
                    const u32* rp = base + (2*py + ir) * 8;
                    const uint4 Wa = *(const uint4*)rp;
                    const uint4 Wb = *(const uint4*)(rp + 4);
                    u32 W8[9] = {Wa.x, Wa.y, Wa.z, Wa.w, Wb.x, Wb.y, Wb.z, Wb.w, 0};
                    u32 e[32];
                    #pragma unroll
                    for (int j = 0; j < 8; ++j) {
                        e[4*j]   = W8[j];
                        e[4*j+1] = alignb(W8[j+1], W8[j], 1);
                        e[4*j+2] = alignb(W8[j+1], W8[j], 2);
                        e[4*j+3] = alignb(W8[j+1], W8[j], 3);
                    }
                    if (ir <= 4) {      // conv row 2py, ky = ir
                        const u32 wa = wrow[ir*2], wb = wrow[ir*2+1];
                        #pragma unroll
                        for (int p = 0; p < 28; ++p)
                            acc0[p] = SDOT4(wa, e[p], SDOT4(wb, e[p+4], acc0[p]));
                    }
                    if (ir >= 1) {      // conv row 2py+1, ky = ir-1
                        const u32 wa = wrow[(ir-1)*2], wb = wrow[(ir-1)*2+1];
                        #pragma unroll
                        for (int p = 0; p < 28; ++p)
                            acc1[p] = SDOT4(wa, e[p], SDOT4(wb, e[p+4], acc1[p]));
                    }
                }
            }
            u32 ow[4] = {0, 0, 0, 0};
            #pragma unroll
            for (int k = 0; k < 14; ++k) {
                const int m = max(max(acc0[2*k], acc0[2*k+1]),
                                  max(acc1[2*k], acc1[2*k+1]));
                const float y = __fadd_rn(__fmul_rn((float)m, c1), cb[c]);
                const float z = __fadd_rn(__fmul_rn(y, cs[c]), cbb[c]);
                const float t = __fdiv_rn(fmaxf(z, 0.f), s_a1);
                const int code = (int)fminf(fmaxf(rintf(t), 0.f), 3.f);
                ow[k >> 2] |= (u32)code << (8 * (k & 3));
            }
            *(uint4*)(a1 + ((size_t)(b*6 + c)*14 + py) * 16) =
                make_uint4(ow[0], ow[1], ow[2], ow[3]);
        }
    }
}

// ---------------------------------------------------------------------------
// Conv2: conv(5x5,6->16) on a1 codes -> maxpool2 -> BN -> relu-quant2b
// Thread = (sample, c_out, pooled_row). a2 out: [B][400] plain bytes.
// ---------------------------------------------------------------------------
#define NS2 3
__global__ __launch_bounds__(256) void k_conv2(
    const uint8_t* __restrict__ a1, const u32* __restrict__ w2p,
    const float* __restrict__ b2, const float* __restrict__ bn2s,
    const float* __restrict__ bn2b, const float* __restrict__ p_sa1,
    const float* __restrict__ p_sw2, const float* __restrict__ p_sa2,
    uint8_t* __restrict__ a2, int B)
{
    __shared__ u32 aL[NS2*336];         // [sl][ci6][row14][4 words]
    __shared__ u32 wp[960];
    __shared__ float cb[16], cs[16], cbb[16];
    const int tid = threadIdx.x;
    const long long b0 = (long long)blockIdx.x * NS2;

    const float c2 = __fmul_rn(p_sa1[0], p_sw2[0]);
    const float s_a2 = p_sa2[0];

    for (int i = tid; i < 960; i += 256) wp[i] = w2p[i];
    if (tid < 16) { cb[tid] = b2[tid]; cs[tid] = bn2s[tid]; cbb[tid] = bn2b[tid]; }

    const u32* a1w = (const u32*)a1;
    const long long wbase = b0 * 336;
    for (int i = tid; i < NS2*336; i += 256)
        if (wbase + i < (long long)B * 336) aL[i] = a1w[wbase + i];
    __syncthreads();

    if (tid < NS2*80) {
        const int sl = tid / 80, o = tid % 80, c = o / 5, py = o % 5;
        const long long b = b0 + sl;
        if (b < B) {
            int acc0[10], acc1[10];
            #pragma unroll
            for (int p = 0; p < 10; ++p) { acc0[p] = 0; acc1[p] = 0; }
            #pragma unroll
            for (int ci = 0; ci < 6; ++ci) {
                const u32* base = &aL[sl*336 + ci*56];
                const u32* wrow = &wp[(c*6 + ci) * 10];
                #pragma unroll
                for (int ir = 0; ir < 6; ++ir) {
                    const uint4 Wv = *(const uint4*)(base + (2*py + ir) * 4);
                    u32 W5[5] = {Wv.x, Wv.y, Wv.z, Wv.w, 0};
                    u32 e[14];
                    #pragma unroll
                    for (int j = 0; j < 4; ++j) {
                        e[4*j] = W5[j];
                        if (4*j+1 < 14) e[4*j+1] = alignb(W5[j+1], W5[j], 1);
                        if (4*j+2 < 14) e[4*j+2] = alignb(W5[j+1], W5[j], 2);
                        if (4*j+3 < 14) e[4*j+3] = alignb(W5[j+1], W5[j], 3);
                    }
                    if (ir <= 4) {
                        const u32 wa = wrow[ir*2], wb = wrow[ir*2+1];
                        #pragma unroll
                        for (int p = 0; p < 10; ++p)
                            acc0[p] = SDOT4(wa, e[p], SDOT4(wb, e[p+4], acc0[p]));
                    }
                    if (ir >= 1) {
                        const u32 wa = wrow[(ir-1)*2], wb = wrow[(ir-1)*2+1];
                        #pragma unroll
                        for (int p = 0; p < 10; ++p)
                            acc1[p] = SDOT4(wa, e[p], SDOT4(wb, e[p+4], acc1[p]));
                    }
                }
            }
            uint8_t* op = a2 + (size_t)b * 400 + c * 25 + py * 5;
            #pragma unroll
            for (int k = 0; k < 5; ++k) {
                const int m = max(max(acc0[2*k], acc0[2*k+1]),
                                  max(acc1[2*k], acc1[2*k+1]));
                const float y = __fadd_rn(__fmul_rn((float)m, c2), cb[c]);
                const float z = __fadd_rn(__fmul_rn(y, cs[c]), cbb[c]);
                const float t = __fdiv_rn(fmaxf(z, 0.f), s_a2);
                op[k] = (uint8_t)(int)fminf(fmaxf(rintf(t), 0.f), 3.f);
            }
        }
    }
}

// ---------------------------------------------------------------------------
// FC: fc1(100x400)+q -> fc2(50x100)+q -> fc3(10x50)+bias. 16 samples/block,
// packed-byte codes, sdot4 inner loops, weights staged once into LDS.
// ---------------------------------------------------------------------------
__global__ __launch_bounds__(256) void k_fc(
    const uint8_t* __restrict__ a2,
    const u32* __restrict__ fw1p, const float* __restrict__ fb1,
    const u32* __restrict__ fw2p, const float* __restrict__ fb2,
    const u32* __restrict__ fw3p, const float* __restrict__ fb3,
    const float* __restrict__ p_sa2, const float* __restrict__ p_sfw1,
    const float* __restrict__ p_sfw2, const float* __restrict__ p_sfw3,
    const float* __restrict__ p_sa3, const float* __restrict__ p_sa4,
    float* __restrict__ out, int B)
{
    __shared__ u32 w1L[10000];
    __shared__ u32 w2L[1250];
    __shared__ u32 w3L[130];
    __shared__ float bb1[100], bb2[52], bb3[12];
    __shared__ u32 xw[16*100];
    __shared__ u32 h1w[16*25];          // 100 bytes / sample
    __shared__ u32 h2w[16*13];          // 52 bytes / sample (pad = 0)
    const int tid = threadIdx.x;
    const long long b0 = (long long)blockIdx.x * 16;

    for (int i = tid; i < 10000; i += 256) w1L[i] = fw1p[i];
    for (int i = tid; i < 1250; i += 256) w2L[i] = fw2p[i];
    if (tid < 130) w3L[tid] = fw3p[tid];
    if (tid < 100) bb1[tid] = fb1[tid];
    else if (tid >= 128 && tid < 178) bb2[tid-128] = fb2[tid-128];
    else if (tid >= 192 && tid < 202) bb3[tid-192] = fb3[tid-192];
    else if (tid >= 224 && tid < 240) h2w[(tid-224)*13 + 12] = 0;
    const u32* a2w = (const u32*)a2;
    const long long wbase = b0 * 100;
    for (int i = tid; i < 1600; i += 256)
        if (wbase + i < (long long)B * 100) xw[i] = a2w[wbase + i];

    const float c3 = __fmul_rn(p_sa2[0], p_sfw1[0]);
    const float c4 = __fmul_rn(p_sa3[0], p_sfw2[0]);
    const float c5 = __fmul_rn(p_sa4[0], p_sfw3[0]);
    const float s_a3 = p_sa3[0], s_a4 = p_sa4[0];
    __syncthreads();

    for (int t = tid; t < 1600; t += 256) {
        const int s = t & 15, o = t >> 4;
        int T = 0;
        const u32* wr = &w1L[o*100];
        const u32* xr = &xw[s*100];
        #pragma unroll 10
        for (int j = 0; j < 100; ++j) T = SDOT4(wr[j], xr[j], T);
        const float y  = __fadd_rn(__fmul_rn((float)T, c3), bb1[o]);
        const float t2 = __fdiv_rn(fmaxf(y, 0.f), s_a3);
        ((uint8_t*)h1w)[s*100 + o] = (uint8_t)(int)fminf(fmaxf(rintf(t2), 0.f), 3.f);
    }
    __syncthreads();

    for (int t = tid; t < 800; t += 256) {
        const int s = t & 15, o = t >> 4;
        int T = 0;
        const u32* wr = &w2L[o*25];
        const u32* xr = &h1w[s*25];
        #pragma unroll
        for (int j = 0; j < 25; ++j) T = SDOT4(wr[j], xr[j], T);
        const float y  = __fadd_rn(__fmul_rn((float)T, c4), bb2[o]);
        const float t2 = __fdiv_rn(fmaxf(y, 0.f), s_a4);
        ((uint8_t*)h2w)[s*52 + o] = (uint8_t)(int)fminf(fmaxf(rintf(t2), 0.f), 3.f);
    }
    __syncthreads();

    for (int t = tid; t < 160; t += 256) {
        const int s = t & 15, o = t >> 4;
        if (b0 + s < B) {
            int T = 0;
            const u32* wr = &w3L[o*13];
            const u32* xr = &h2w[s*13];
            #pragma unroll
            for (int j = 0; j < 13; ++j) T = SDOT4(wr[j], xr[j], T);
            out[(size_t)(b0 + s)*10 + o] = __fadd_rn(__fmul_rn((float)T, c5), bb3[o]);
        }
    }
}

// ---------------------------------------------------------------------------
extern "C" void kernel_launch(void* const* d_in, const int* in_sizes, int n_in,
                              void* d_out, int out_size, void* d_ws, size_t ws_size,
                              hipStream_t stream)
{
    const float* x    = (const float*)d_in[0];
    const float* w1   = (const float*)d_in[1];
    const float* b1   = (const float*)d_in[2];
    const float* w2   = (const float*)d_in[3];
    const float* b2   = (const float*)d_in[4];
    const float* fw1  = (const float*)d_in[5];
    const float* fb1  = (const float*)d_in[6];
    const float* fw2  = (const float*)d_in[7];
    const float* fb2  = (const float*)d_in[8];
    const float* fw3  = (const float*)d_in[9];
    const float* fb3  = (const float*)d_in[10];
    const float* bn1s = (const float*)d_in[11];
    const float* bn1b = (const float*)d_in[12];
    const float* bn2s = (const float*)d_in[13];
    const float* bn2b = (const float*)d_in[14];
    const float* s_in = (const float*)d_in[15];
    const float* s_w1 = (const float*)d_in[16];
    const float* s_w2 = (const float*)d_in[17];
    const float* s_fw1= (const float*)d_in[18];
    const float* s_fw2= (const float*)d_in[19];
    const float* s_fw3= (const float*)d_in[20];
    const float* s_a1 = (const float*)d_in[21];
    const float* s_a2 = (const float*)d_in[22];
    const float* s_a3 = (const float*)d_in[23];
    const float* s_a4 = (const float*)d_in[24];

    int B = out_size / 10;
    if (B <= 0) B = 16384;

    // workspace carve (all 16B aligned)
    uint8_t* ws  = (uint8_t*)d_ws;
    uint8_t* a1  = ws;                                   // B*1344
    uint8_t* a2  = a1 + (size_t)B * 1344;                // B*400
    uint8_t* p   = a2 + (size_t)B * 400;
    u32* w1p  = (u32*)p;            p += 180 * 4;        // 720
    u32* w2p  = (u32*)p;            p += 960 * 4;        // 3840
    u32* fw1p = (u32*)p;            p += 10000 * 4;      // 40000
    u32* fw2p = (u32*)p;            p += 1250 * 4 + 8;   // 5008 (keep 16B align)
    u32* fw3p = (u32*)p;

    k_prep<<<1, 256, 0, stream>>>(w1, w2, fw1, fw2, fw3,
                                  w1p, w2p, fw1p, fw2p, fw3p);
    const int g1 = (B + NS1 - 1) / NS1;
    k_conv1<<<g1, 256, 0, stream>>>(x, w1p, b1, bn1s, bn1b, s_in, s_w1, s_a1, a1, B);
    const int g2 = (B + NS2 - 1) / NS2;
    k_conv2<<<g2, 256, 0, stream>>>(a1, w2p, b2, bn2s, bn2b, s_a1, s_w2, s_a2, a2, B);
    k_fc<<<(B + 15) / 16, 256, 0, stream>>>(a2, fw1p, fb1, fw2p, fb2, fw3p, fb3,
                                            s_a2, s_fw1, s_fw2, s_fw3, s_a3, s_a4,
                                            (float*)d_out, B);
}